// Round 2
// baseline (313.636 us; speedup 1.0000x reference)
//
#include <hip/hip_runtime.h>
#include <hip/hip_cooperative_groups.h>
#include <hip/hip_bf16.h>
#include <math.h>

namespace cg = cooperative_groups;

#define S_LEN  2048
#define DMODEL 512
#define NHEADS 8
#define DK     64
#define WIN    64

static constexpr float SCALE = 0.125f;

typedef short bf16x8 __attribute__((ext_vector_type(8)));
typedef float f32x4  __attribute__((ext_vector_type(4)));

// ---------------------------------------------------------------------------
// helpers
// ---------------------------------------------------------------------------
__device__ __forceinline__ short bfh(float v)
{
    __hip_bfloat16 b = __float2bfloat16(v);
    return *reinterpret_cast<short*>(&b);
}
__device__ __forceinline__ float bf2f(short s)
{
    __hip_bfloat16 b = *reinterpret_cast<__hip_bfloat16*>(&s);
    return __bfloat162float(b);
}
__device__ __forceinline__ void split1(float v, short& h, short& l)
{
    h = bfh(v);
    l = bfh(v - bf2f(h));
}

// async global->LDS, 16B per lane; lds dest = wave-uniform base + lane*16
__device__ __forceinline__ void dma16(const void* g, void* l)
{
    __builtin_amdgcn_global_load_lds(
        (const __attribute__((address_space(1))) unsigned int*)g,
        (__attribute__((address_space(3))) unsigned int*)l, 16, 0, 0);
}

// ---------------------------------------------------------------------------
// Fused cooperative kernel: 512 blocks x 256 thr, 2 blocks/CU co-resident.
//   phase 0: prep   (x -> xh/xl split, W -> bf16)
//   phase 1: QKV GEMM (each block: one 64row x 32col tile for z=0,1,2)
//   phase 2: banded attention (one (head, 32-q tile) per block)
//   phase 3: output GEMM (one 64row x 32col tile per block)
// grid.sync() between phases replaces 3 kernel launch+ramp+drain cycles.
// ---------------------------------------------------------------------------
struct KParams {
    const float *x, *Wq, *bq, *Wk, *bk, *Wv, *bv, *Wo, *bo;
    float* out;
    short *qb, *kb, *vbt, *abh, *xh, *xl, *wqb, *wkb, *wvb, *wob;
};

__global__ __launch_bounds__(256, 2)
void fused(KParams p)
{
    // 62464 B arena: GEMM phases use first 32 KB (sW); attention uses all.
    __shared__ __align__(16) char smem[62464];
    cg::grid_group grid = cg::this_grid();

    const int bid  = blockIdx.x;
    const int tid  = threadIdx.x;
    const int lane = tid & 63;
    const int wv   = tid >> 6;
    const int col  = lane & 15;
    const int quad = lane >> 4;

    // ================= phase 0: prep =================
    {
        for (int i = bid * 256 + tid; i < 262144; i += 131072) {
            const float4 v = ((const float4*)p.x)[i];
            short4 h4, l4;
            split1(v.x, h4.x, l4.x);
            split1(v.y, h4.y, l4.y);
            split1(v.z, h4.z, l4.z);
            split1(v.w, h4.w, l4.w);
            ((short4*)p.xh)[i] = h4;
            ((short4*)p.xl)[i] = l4;
        }
        for (int u = bid * 256 + tid; u < 262144; u += 131072) {
            const int w = u >> 16;          // 0..3 -> Wq,Wk,Wv,Wo
            const int i = u & 65535;
            const float* s = (w == 0) ? p.Wq : (w == 1) ? p.Wk : (w == 2) ? p.Wv : p.Wo;
            short*       d = (w == 0) ? p.wqb : (w == 1) ? p.wkb : (w == 2) ? p.wvb : p.wob;
            const float4 v = ((const float4*)s)[i];
            short4 o;
            o.x = bfh(v.x); o.y = bfh(v.y); o.z = bfh(v.z); o.w = bfh(v.w);
            ((short4*)d)[i] = o;
        }
    }
    grid.sync();

    // ================= phase 1: QKV GEMM =================
    {
        short* sW = (short*)smem;                  // 32 cols x 512 k = 32 KB
        const int ct   = bid & 15;                 // 16 col-tiles of 32
        const int rt   = bid >> 4;                 // 32 row-tiles of 64
        const int col0 = ct * 32;
        const int m    = rt * 64 + wv * 16 + col;  // this wave's A row

        for (int z = 0; z < 3; ++z) {
            const short* Bg   = (z == 0) ? p.wqb : (z == 1) ? p.wkb : p.wvb;
            const float* bias = (z == 0) ? p.bq  : (z == 1) ? p.bk  : p.bv;

            __syncthreads();   // prior z's sW reads done
            // stage 32 W-rows x 1KB; LDS[i][l] = G[i][l ^ (i&7)]
            for (int i = wv; i < 32; i += 4)
                dma16(Bg + (size_t)(col0 + i) * 512 + (size_t)((lane ^ (i & 7)) * 8),
                      sW + i * 512);
            __syncthreads();   // DMA drain

            f32x4 acc[2];
            acc[0] = (f32x4)0.0f;
            acc[1] = (f32x4)0.0f;

#pragma unroll 4
            for (int kc = 0; kc < 16; ++kc) {
                const size_t aoff = (size_t)m * 512 + kc * 32 + quad * 8;
                const bf16x8 ah = *(const bf16x8*)(p.xh + aoff);
                const bf16x8 al = *(const bf16x8*)(p.xl + aoff);
#pragma unroll
                for (int nj = 0; nj < 2; ++nj) {
                    const int n = nj * 16 + col;
                    const int c = kc * 4 + quad;
                    const bf16x8 bf = *(const bf16x8*)&sW[n * 512 + ((c ^ (n & 7)) * 8)];
                    acc[nj] = __builtin_amdgcn_mfma_f32_16x16x32_bf16(ah, bf, acc[nj], 0, 0, 0);
                    acc[nj] = __builtin_amdgcn_mfma_f32_16x16x32_bf16(al, bf, acc[nj], 0, 0, 0);
                }
            }

#pragma unroll
            for (int nj = 0; nj < 2; ++nj) {
                const int cc = col0 + nj * 16 + col;
                const float bias_v = bias[cc];
#pragma unroll
                for (int e = 0; e < 4; ++e) {
                    const int row = rt * 64 + wv * 16 + quad * 4 + e;
                    const float val = acc[nj][e] + bias_v;
                    if (z == 0)      p.qb[(size_t)row * 512 + cc] = bfh(val);
                    else if (z == 1) p.kb[(size_t)row * 512 + cc] = bfh(val);
                    else             p.vbt[(size_t)cc * 2048 + row] = bfh(val);
                }
            }
        }
    }
    grid.sync();

    // ================= phase 2: banded attention =================
    {
        short* VtS = (short*)smem;                  // 64 x 256 shorts, 32 KB
        short* KS  = (short*)(smem + 32768);        // 192 x 64 shorts, 24 KB
        short* QS  = (short*)(smem + 57344);        // 32 x 64 shorts, 4 KB
        float (*pmax)[32] = (float(*)[32])(smem + 61440);
        float (*psum)[32] = (float(*)[32])(smem + 61952);
        short* PS = KS;                             // P [32][200], after QK

        const int h  = bid >> 6;                    // 8 heads
        const int t0 = (bid & 63) * 32;             // 64 q-tiles

        // ---- DMA staging: Q (4 issues), K (24) — 8-row groups of 128B ----
        {
            const int lr = lane >> 3;
            const int lc = lane & 7;
            for (int i = wv; i < 28; i += 4) {
                const short* src; short* dst; int r;
                if (i < 4) {
                    r = i * 8 + lr;
                    src = p.qb + (size_t)(t0 + r) * 512 + h * 64;
                    dst = QS + i * 512;
                } else {
                    const int g = i - 4;
                    r = g * 8 + lr;
                    int pos = t0 - 64 + r;
                    pos = pos < 0 ? 0 : (pos > 2047 ? 2047 : pos);   // masked later
                    src = p.kb + (size_t)pos * 512 + h * 64;
                    dst = KS + g * 512;
                }
                const int cs = lc ^ (r & 7);
                dma16(src + cs * 8, dst);
            }
            // V^T window: 64 dims x 24 chunks (192 pos), rows padded to 32
            for (int i = wv; i < 32; i += 4) {
                const int q = i * 64 + lane;
                const int d = q >> 5;            // dim 0..63
                const int b = q & 31;            // dest chunk in row
                const int j0 = (b < 24) ? b : 0; // dead chunks load dummy
                const int j = j0 ^ (d & 7);
                int p0 = t0 - 64 + j * 8;
                p0 = p0 < 0 ? 0 : (p0 > 2040 ? 2040 : p0);
                dma16(p.vbt + (size_t)(h * 64 + d) * 2048 + p0, VtS + i * 512);
            }
        }
        __syncthreads();

        // ---- QK^T: wave covers positions [wv*48, wv*48+48) ----
        f32x4 sacc[2][3];
#pragma unroll
        for (int mi = 0; mi < 2; ++mi)
#pragma unroll
            for (int nj = 0; nj < 3; ++nj)
                sacc[mi][nj] = (f32x4)0.0f;

#pragma unroll
        for (int ks = 0; ks < 2; ++ks) {
            const int q0 = ks * 4 + quad;
            bf16x8 aq[2];
#pragma unroll
            for (int mi = 0; mi < 2; ++mi) {
                const int mm = mi * 16 + col;
                const int pp = q0 ^ (mm & 7);
                aq[mi] = *(const bf16x8*)&QS[mm * 64 + pp * 8];
            }
#pragma unroll
            for (int nj = 0; nj < 3; ++nj) {
                const int n = wv * 48 + nj * 16 + col;
                const int pp = q0 ^ (n & 7);
                const bf16x8 bkf = *(const bf16x8*)&KS[n * 64 + pp * 8];
#pragma unroll
                for (int mi = 0; mi < 2; ++mi)
                    sacc[mi][nj] = __builtin_amdgcn_mfma_f32_16x16x32_bf16(aq[mi], bkf, sacc[mi][nj], 0, 0, 0);
            }
        }

        // ---- mask + scale ----
        float pv[2][3][4];
#pragma unroll
        for (int mi = 0; mi < 2; ++mi)
#pragma unroll
            for (int nj = 0; nj < 3; ++nj)
#pragma unroll
                for (int e = 0; e < 4; ++e) {
                    const int r32 = mi * 16 + quad * 4 + e;
                    const int n   = wv * 48 + nj * 16 + col;
                    const int pos = t0 - 64 + n;
                    const int d   = n - r32;
                    const bool valid = (pos >= 0) && (pos < S_LEN) && (d >= 0) && (d <= 128);
                    pv[mi][nj][e] = valid ? sacc[mi][nj][e] * SCALE : -__builtin_inff();
                }

        // ---- wave-partial row max ----
#pragma unroll
        for (int mi = 0; mi < 2; ++mi)
#pragma unroll
            for (int e = 0; e < 4; ++e) {
                float mx = fmaxf(fmaxf(pv[mi][0][e], pv[mi][1][e]), pv[mi][2][e]);
#pragma unroll
                for (int off = 1; off < 16; off <<= 1)
                    mx = fmaxf(mx, __shfl_xor(mx, off));
                if ((lane & 15) == 0) pmax[wv][mi * 16 + quad * 4 + e] = mx;
            }
        __syncthreads();   // pmax done; K/Q reads done -> P may overwrite KS

        // ---- exp + wave-partial sums + write P (bf16) ----
#pragma unroll
        for (int mi = 0; mi < 2; ++mi)
#pragma unroll
            for (int e = 0; e < 4; ++e) {
                const int r32 = mi * 16 + quad * 4 + e;
                const float m = fmaxf(fmaxf(pmax[0][r32], pmax[1][r32]),
                                      fmaxf(pmax[2][r32], pmax[3][r32]));
                float ss = 0.f;
#pragma unroll
                for (int nj = 0; nj < 3; ++nj) {
                    const float pe = __expf(pv[mi][nj][e] - m);
                    pv[mi][nj][e] = pe;
                    ss += pe;
                }
#pragma unroll
                for (int off = 1; off < 16; off <<= 1)
                    ss += __shfl_xor(ss, off);
                if ((lane & 15) == 0) psum[wv][r32] = ss;
#pragma unroll
                for (int nj = 0; nj < 3; ++nj) {
                    const int n = wv * 48 + nj * 16 + col;
                    PS[r32 * 200 + n] = bfh(pv[mi][nj][e]);
                }
            }
        __syncthreads();

        // ---- PV ----
        const int mi = wv >> 1;
        f32x4 oacc[2];
        oacc[0] = (f32x4)0.0f;
        oacc[1] = (f32x4)0.0f;
#pragma unroll
        for (int ks = 0; ks < 6; ++ks) {
            const bf16x8 pa = *(const bf16x8*)&PS[(mi * 16 + col) * 200 + ks * 32 + quad * 8];
#pragma unroll
            for (int t = 0; t < 2; ++t) {
                const int d = ((wv & 1) * 2 + t) * 16 + col;
                const int j = (ks * 4 + quad) ^ (d & 7);
                const bf16x8 vf = *(const bf16x8*)&VtS[d * 256 + j * 8];
                oacc[t] = __builtin_amdgcn_mfma_f32_16x16x32_bf16(pa, vf, oacc[t], 0, 0, 0);
            }
        }

        // ---- epilogue: normalize, write bf16 for out-GEMM ----
        float linv[4];
#pragma unroll
        for (int e = 0; e < 4; ++e) {
            const int r32 = mi * 16 + quad * 4 + e;
            linv[e] = 1.0f / (psum[0][r32] + psum[1][r32] + psum[2][r32] + psum[3][r32]);
        }
#pragma unroll
        for (int t = 0; t < 2; ++t) {
            const int nj = (wv & 1) * 2 + t;
#pragma unroll
            for (int e = 0; e < 4; ++e) {
                const int r32 = mi * 16 + quad * 4 + e;
                const float val = oacc[t][e] * linv[e];
                const size_t idx = (size_t)(t0 + r32) * 512 + h * 64 + nj * 16 + col;
                p.abh[idx] = bfh(val);
            }
        }
    }
    grid.sync();

    // ================= phase 3: output GEMM =================
    {
        short* sW = (short*)smem;                  // 32 cols x 512 k = 32 KB
        const int ct   = bid & 15;
        const int rt   = bid >> 4;
        const int col0 = ct * 32;
        const int m    = rt * 64 + wv * 16 + col;

        for (int i = wv; i < 32; i += 4)
            dma16(p.wob + (size_t)(col0 + i) * 512 + (size_t)((lane ^ (i & 7)) * 8),
                  sW + i * 512);
        __syncthreads();

        f32x4 acc[2];
        acc[0] = (f32x4)0.0f;
        acc[1] = (f32x4)0.0f;

#pragma unroll 4
        for (int kc = 0; kc < 16; ++kc) {
            const bf16x8 af = *(const bf16x8*)(p.abh + (size_t)m * 512 + kc * 32 + quad * 8);
#pragma unroll
            for (int nj = 0; nj < 2; ++nj) {
                const int n = nj * 16 + col;
                const int c = kc * 4 + quad;
                const bf16x8 bf = *(const bf16x8*)&sW[n * 512 + ((c ^ (n & 7)) * 8)];
                acc[nj] = __builtin_amdgcn_mfma_f32_16x16x32_bf16(af, bf, acc[nj], 0, 0, 0);
            }
        }

#pragma unroll
        for (int nj = 0; nj < 2; ++nj) {
            const int cc = col0 + nj * 16 + col;
            const float bias_v = p.bo[cc];
#pragma unroll
            for (int e = 0; e < 4; ++e) {
                const int row = rt * 64 + wv * 16 + quad * 4 + e;
                p.out[(size_t)row * 512 + cc] = acc[nj][e] + bias_v;
            }
        }
    }
}

// ---------------------------------------------------------------------------
extern "C" void kernel_launch(void* const* d_in, const int* in_sizes, int n_in,
                              void* d_out, int out_size, void* d_ws, size_t ws_size,
                              hipStream_t stream)
{
    char* ws = (char*)d_ws;
    KParams p;
    p.x  = (const float*)d_in[0];
    p.Wq = (const float*)d_in[1];
    p.bq = (const float*)d_in[2];
    p.Wk = (const float*)d_in[3];
    p.bk = (const float*)d_in[4];
    p.Wv = (const float*)d_in[5];
    p.bv = (const float*)d_in[6];
    p.Wo = (const float*)d_in[7];
    p.bo = (const float*)d_in[8];
    p.out = (float*)d_out;
    p.qb  = (short*)(ws);                          // 2 MB
    p.kb  = (short*)(ws + (2u << 20));             // 2 MB
    p.vbt = (short*)(ws + (4u << 20));             // 2 MB (transposed V)
    p.abh = (short*)(ws + (6u << 20));             // 2 MB (attn out bf16)
    p.xh  = (short*)(ws + (8u << 20));             // 2 MB
    p.xl  = (short*)(ws + (10u << 20));            // 2 MB
    p.wqb = (short*)(ws + (12u << 20));            // 0.5 MB each
    p.wkb = (short*)(ws + (12u << 20) + 1 * (512u << 10));
    p.wvb = (short*)(ws + (12u << 20) + 2 * (512u << 10));
    p.wob = (short*)(ws + (12u << 20) + 3 * (512u << 10));

    void* args[] = { &p };
    hipLaunchCooperativeKernel((const void*)fused, dim3(512), dim3(256),
                               args, 0, stream);
}

// Round 4
// 115.199 us; speedup vs baseline: 2.7226x; 2.7226x over previous
//
#include <hip/hip_runtime.h>
#include <hip/hip_bf16.h>
#include <math.h>

#define S_LEN  2048
#define DMODEL 512
#define NHEADS 8
#define DK     64
#define WIN    64

static constexpr float SCALE = 0.125f;

typedef short bf16x8 __attribute__((ext_vector_type(8)));
typedef float f32x4  __attribute__((ext_vector_type(4)));

// ---------------------------------------------------------------------------
// helpers
// ---------------------------------------------------------------------------
__device__ __forceinline__ short bfh(float v)
{
    __hip_bfloat16 b = __float2bfloat16(v);
    return *reinterpret_cast<short*>(&b);
}
__device__ __forceinline__ float bf2f(short s)
{
    __hip_bfloat16 b = *reinterpret_cast<__hip_bfloat16*>(&s);
    return __bfloat162float(b);
}
__device__ __forceinline__ void split1(float v, short& h, short& l)
{
    h = bfh(v);
    l = bfh(v - bf2f(h));
}

// async global->LDS, 16B per lane; lds dest = wave-uniform base + lane*16
__device__ __forceinline__ void dma16(const void* g, void* l)
{
    __builtin_amdgcn_global_load_lds(
        (const __attribute__((address_space(1))) unsigned int*)g,
        (__attribute__((address_space(3))) unsigned int*)l, 16, 0, 0);
}

// ---------------------------------------------------------------------------
// prep: z=0 -> x split into (xh, xl); z=1..4 -> W cast to bf16
// ---------------------------------------------------------------------------
__global__ __launch_bounds__(256)
void prep(const float* __restrict__ x,
          const float* __restrict__ wq, const float* __restrict__ wk,
          const float* __restrict__ wv, const float* __restrict__ wo,
          short* __restrict__ xh, short* __restrict__ xl,
          short* __restrict__ wqb, short* __restrict__ wkb,
          short* __restrict__ wvb, short* __restrict__ wob)
{
    const int z = blockIdx.z;
    if (z == 0) {
        for (int i = blockIdx.x * 256 + threadIdx.x; i < 262144; i += gridDim.x * 256) {
            const float4 v = ((const float4*)x)[i];
            short4 h4, l4;
            split1(v.x, h4.x, l4.x);
            split1(v.y, h4.y, l4.y);
            split1(v.z, h4.z, l4.z);
            split1(v.w, h4.w, l4.w);
            ((short4*)xh)[i] = h4;
            ((short4*)xl)[i] = l4;
        }
    } else {
        const float* s; short* d;
        switch (z) {
            case 1:  s = wq; d = wqb; break;
            case 2:  s = wk; d = wkb; break;
            case 3:  s = wv; d = wvb; break;
            default: s = wo; d = wob; break;
        }
        for (int i = blockIdx.x * 256 + threadIdx.x; i < 65536; i += gridDim.x * 256) {
            const float4 v = ((const float4*)s)[i];
            short4 o;
            o.x = bfh(v.x); o.y = bfh(v.y); o.z = bfh(v.z); o.w = bfh(v.w);
            ((short4*)d)[i] = o;
        }
    }
}

// ---------------------------------------------------------------------------
// QKV GEMM v9: round-0 tiling (32-row x 64-col, grid (8,64,3), 128 thr =
// 2 waves) but with DOUBLE-BUFFERED phase staging: stage(ph+1) issued
// before compute(ph), single barrier per phase. W-DMA latency hides under
// the 32-MFMA burst; the barrier's vmcnt(0) drain is then nearly free.
// z=0 -> Q bf16, z=1 -> K bf16, z=2 -> V^T bf16 [dim][pos].
// ---------------------------------------------------------------------------
__global__ __launch_bounds__(128)
void gemm_qkv9(const short* __restrict__ xh, const short* __restrict__ xl,
               const short* __restrict__ wqb, const short* __restrict__ wkb,
               const short* __restrict__ wvb,
               const float* __restrict__ bq, const float* __restrict__ bk,
               const float* __restrict__ bv,
               short* __restrict__ qb, short* __restrict__ kb,
               short* __restrict__ vbt)
{
    __shared__ __align__(16) short sW[2][64 * 128];   // 2 x 16 KB dbuf

    const int z = blockIdx.z;
    const short* Bg   = (z == 0) ? wqb : (z == 1) ? wkb : wvb;
    const float* bias = (z == 0) ? bq  : (z == 1) ? bk  : bv;
    const int row0 = blockIdx.y * 32;
    const int col0 = blockIdx.x * 64;
    const int tid  = threadIdx.x;
    const int lane = tid & 63;
    const int wv   = tid >> 6;
    const int col  = lane & 15;
    const int quad = lane >> 4;
    const int m    = row0 + wv * 16 + col;       // this wave's A row

    // stage phase ph into buffer b: 64 rows x 16 chunks (16B), issue i = rows 4i..4i+3
    // LDS[r][c] = G[r][c ^ (r&7)]  (XOR involution per row)
#define STAGE_W(b, ph)                                                          \
    for (int i = wv; i < 16; i += 2) {                                          \
        const int r = i * 4 + (lane >> 4);                                      \
        const int c = lane & 15;                                                \
        const int j = c ^ (r & 7);                                              \
        dma16(Bg + (size_t)(col0 + r) * 512 + (ph) * 128 + j * 8,               \
              &sW[b][i * 512]);                                                 \
    }

    STAGE_W(0, 0)
    __syncthreads();   // prologue drain

    f32x4 acc[4];
#pragma unroll
    for (int nj = 0; nj < 4; ++nj)
        acc[nj] = (f32x4)0.0f;

    for (int ph = 0; ph < 4; ++ph) {
        const int b = ph & 1;
        if (ph < 3) {                       // issue next tile, no wait
            STAGE_W(b ^ 1, ph + 1)
        }
#pragma unroll
        for (int kc = 0; kc < 4; ++kc) {
            const size_t aoff = (size_t)m * 512 + ph * 128 + kc * 32 + quad * 8;
            const bf16x8 ah = *(const bf16x8*)(xh + aoff);
            const bf16x8 al = *(const bf16x8*)(xl + aoff);
#pragma unroll
            for (int nj = 0; nj < 4; ++nj) {
                const int n = nj * 16 + col;
                const int c = kc * 4 + quad;
                const bf16x8 bf = *(const bf16x8*)&sW[b][n * 128 + (c ^ (n & 7)) * 8];
                acc[nj] = __builtin_amdgcn_mfma_f32_16x16x32_bf16(ah, bf, acc[nj], 0, 0, 0);
                acc[nj] = __builtin_amdgcn_mfma_f32_16x16x32_bf16(al, bf, acc[nj], 0, 0, 0);
            }
        }
        __syncthreads();   // drains stage(ph+1) (mostly complete) + releases buf b
    }
#undef STAGE_W

    // epilogue
#pragma unroll
    for (int nj = 0; nj < 4; ++nj) {
        const int cc = col0 + nj * 16 + col;
        const float bias_v = bias[cc];
#pragma unroll
        for (int e = 0; e < 4; ++e) {
            const int row = row0 + wv * 16 + quad * 4 + e;
            const float val = acc[nj][e] + bias_v;
            if (z == 0) {
                qb[(size_t)row * 512 + cc] = bfh(val);        // single bf16 Q
            } else if (z == 1) {
                kb[(size_t)row * 512 + cc] = bfh(val);
            } else {
                vbt[(size_t)cc * 2048 + row] = bfh(val);      // transposed
            }
        }
    }
}

// ---------------------------------------------------------------------------
// Output projection v9: same dbuf pipelined staging; A = attn output bf16.
// grid (8,64) = 512 blocks, 128 thr.
// ---------------------------------------------------------------------------
__global__ __launch_bounds__(128)
void gemm_out9(const short* __restrict__ ah_g,
               const short* __restrict__ wob, const float* __restrict__ bo,
               float* __restrict__ out)
{
    __shared__ __align__(16) short sW[2][64 * 128];   // 2 x 16 KB

    const int row0 = blockIdx.y * 32;
    const int col0 = blockIdx.x * 64;
    const int tid  = threadIdx.x;
    const int lane = tid & 63;
    const int wv   = tid >> 6;
    const int col  = lane & 15;
    const int quad = lane >> 4;
    const int m    = row0 + wv * 16 + col;

#define STAGE_W(b, ph)                                                          \
    for (int i = wv; i < 16; i += 2) {                                          \
        const int r = i * 4 + (lane >> 4);                                      \
        const int c = lane & 15;                                                \
        const int j = c ^ (r & 7);                                              \
        dma16(wob + (size_t)(col0 + r) * 512 + (ph) * 128 + j * 8,              \
              &sW[b][i * 512]);                                                 \
    }

    STAGE_W(0, 0)
    __syncthreads();

    f32x4 acc[4];
#pragma unroll
    for (int nj = 0; nj < 4; ++nj)
        acc[nj] = (f32x4)0.0f;

    for (int ph = 0; ph < 4; ++ph) {
        const int b = ph & 1;
        if (ph < 3) {
            STAGE_W(b ^ 1, ph + 1)
        }
#pragma unroll
        for (int kc = 0; kc < 4; ++kc) {
            const bf16x8 af = *(const bf16x8*)(ah_g + (size_t)m * 512 + ph * 128 + kc * 32 + quad * 8);
#pragma unroll
            for (int nj = 0; nj < 4; ++nj) {
                const int n = nj * 16 + col;
                const int c = kc * 4 + quad;
                const bf16x8 bf = *(const bf16x8*)&sW[b][n * 128 + (c ^ (n & 7)) * 8];
                acc[nj] = __builtin_amdgcn_mfma_f32_16x16x32_bf16(af, bf, acc[nj], 0, 0, 0);
            }
        }
        __syncthreads();
    }
#undef STAGE_W

#pragma unroll
    for (int nj = 0; nj < 4; ++nj) {
        const int cc = col0 + nj * 16 + col;
        const float bias_v = bo[cc];
#pragma unroll
        for (int e = 0; e < 4; ++e) {
            const int row = row0 + wv * 16 + quad * 4 + e;
            out[(size_t)row * 512 + cc] = acc[nj][e] + bias_v;
        }
    }
}

// ---------------------------------------------------------------------------
// MFMA banded attention v7: round-0 body, but V^T staging is issued AFTER
// the Q/K drain and flies under QK^T+max compute (T14 async-stage split).
// Block = (head, 32-q tile), 256 thr = 4 waves.
// ---------------------------------------------------------------------------
__global__ __launch_bounds__(256)
void banded_attn7(const short* __restrict__ qb, const short* __restrict__ kb,
                  const short* __restrict__ vbt, short* __restrict__ abh)
{
    __shared__ __align__(16) short VtS[64 * 256];   // V^T [dim][32 chunks]
    __shared__ __align__(16) short KS [192 * 64];   // K window; aliased by P
    __shared__ __align__(16) short QS [32 * 64];
    __shared__ float pmax[4][32];
    __shared__ float psum[4][32];
    short* PS = KS;                                 // P [32][200], after QK

    const int h    = blockIdx.x;
    const int t0   = blockIdx.y * 32;
    const int tid  = threadIdx.x;
    const int lane = tid & 63;
    const int wv   = tid >> 6;
    const int col  = lane & 15;
    const int quad = lane >> 4;

    // ---- DMA staging: Q (4 issues), K (24) — 8-row groups of 128B ----
    {
        const int lr = lane >> 3;
        const int lc = lane & 7;
        for (int i = wv; i < 28; i += 4) {
            const short* src; short* dst; int r;
            if (i < 4) {
                r = i * 8 + lr;
                src = qb + (size_t)(t0 + r) * 512 + h * 64;
                dst = QS + i * 512;
            } else {
                const int g = i - 4;
                r = g * 8 + lr;
                int pos = t0 - 64 + r;
                pos = pos < 0 ? 0 : (pos > 2047 ? 2047 : pos);   // masked later
                src = kb + (size_t)pos * 512 + h * 64;
                dst = KS + g * 512;
            }
            const int cs = lc ^ (r & 7);
            dma16(src + cs * 8, dst);
        }
    }
    __syncthreads();   // drain Q+K only (28 KB) — V not yet issued

    // ---- V^T window issued now: flies under QK^T + max compute ----
    for (int i = wv; i < 32; i += 4) {
        const int q = i * 64 + lane;
        const int d = q >> 5;            // dim 0..63
        const int b = q & 31;            // dest chunk in row
        const int j0 = (b < 24) ? b : 0; // dead chunks load dummy
        const int j = j0 ^ (d & 7);
        int p0 = t0 - 64 + j * 8;
        p0 = p0 < 0 ? 0 : (p0 > 2040 ? 2040 : p0);
        dma16(vbt + (size_t)(h * 64 + d) * 2048 + p0, VtS + i * 512);
    }

    // ---- QK^T: wave covers positions [wv*48, wv*48+48) ----
    f32x4 sacc[2][3];
#pragma unroll
    for (int mi = 0; mi < 2; ++mi)
#pragma unroll
        for (int nj = 0; nj < 3; ++nj)
            sacc[mi][nj] = (f32x4)0.0f;

#pragma unroll
    for (int ks = 0; ks < 2; ++ks) {
        const int q0 = ks * 4 + quad;
        bf16x8 aq[2];
#pragma unroll
        for (int mi = 0; mi < 2; ++mi) {
            const int mm = mi * 16 + col;
            const int p = q0 ^ (mm & 7);
            aq[mi] = *(const bf16x8*)&QS[mm * 64 + p * 8];
        }
#pragma unroll
        for (int nj = 0; nj < 3; ++nj) {
            const int n = wv * 48 + nj * 16 + col;
            const int p = q0 ^ (n & 7);
            const bf16x8 bkf = *(const bf16x8*)&KS[n * 64 + p * 8];
#pragma unroll
            for (int mi = 0; mi < 2; ++mi)
                sacc[mi][nj] = __builtin_amdgcn_mfma_f32_16x16x32_bf16(aq[mi], bkf, sacc[mi][nj], 0, 0, 0);
        }
    }

    // ---- mask + scale ----
    float pv[2][3][4];
#pragma unroll
    for (int mi = 0; mi < 2; ++mi)
#pragma unroll
        for (int nj = 0; nj < 3; ++nj)
#pragma unroll
            for (int e = 0; e < 4; ++e) {
                const int r32 = mi * 16 + quad * 4 + e;
                const int n   = wv * 48 + nj * 16 + col;
                const int pos = t0 - 64 + n;
                const int d   = n - r32;
                const bool valid = (pos >= 0) && (pos < S_LEN) && (d >= 0) && (d <= 128);
                pv[mi][nj][e] = valid ? sacc[mi][nj][e] * SCALE : -__builtin_inff();
            }

    // ---- wave-partial row max ----
#pragma unroll
    for (int mi = 0; mi < 2; ++mi)
#pragma unroll
        for (int e = 0; e < 4; ++e) {
            float mx = fmaxf(fmaxf(pv[mi][0][e], pv[mi][1][e]), pv[mi][2][e]);
#pragma unroll
            for (int off = 1; off < 16; off <<= 1)
                mx = fmaxf(mx, __shfl_xor(mx, off));
            if ((lane & 15) == 0) pmax[wv][mi * 16 + quad * 4 + e] = mx;
        }
    __syncthreads();   // pmax done; K/Q reads done -> P may overwrite KS; V drained

    // ---- exp + wave-partial sums + write P (bf16) ----
#pragma unroll
    for (int mi = 0; mi < 2; ++mi)
#pragma unroll
        for (int e = 0; e < 4; ++e) {
            const int r32 = mi * 16 + quad * 4 + e;
            const float m = fmaxf(fmaxf(pmax[0][r32], pmax[1][r32]),
                                  fmaxf(pmax[2][r32], pmax[3][r32]));
            float ss = 0.f;
#pragma unroll
            for (int nj = 0; nj < 3; ++nj) {
                const float p = __expf(pv[mi][nj][e] - m);
                pv[mi][nj][e] = p;
                ss += p;
            }
#pragma unroll
            for (int off = 1; off < 16; off <<= 1)
                ss += __shfl_xor(ss, off);
            if ((lane & 15) == 0) psum[wv][r32] = ss;
#pragma unroll
            for (int nj = 0; nj < 3; ++nj) {
                const int n = wv * 48 + nj * 16 + col;
                PS[r32 * 200 + n] = bfh(pv[mi][nj][e]);
            }
        }
    __syncthreads();

    // ---- PV ----
    const int mi = wv >> 1;
    f32x4 oacc[2];
    oacc[0] = (f32x4)0.0f;
    oacc[1] = (f32x4)0.0f;
#pragma unroll
    for (int ks = 0; ks < 6; ++ks) {
        const bf16x8 pa = *(const bf16x8*)&PS[(mi * 16 + col) * 200 + ks * 32 + quad * 8];
#pragma unroll
        for (int t = 0; t < 2; ++t) {
            const int d = ((wv & 1) * 2 + t) * 16 + col;
            const int j = (ks * 4 + quad) ^ (d & 7);
            const bf16x8 vf = *(const bf16x8*)&VtS[d * 256 + j * 8];
            oacc[t] = __builtin_amdgcn_mfma_f32_16x16x32_bf16(pa, vf, oacc[t], 0, 0, 0);
        }
    }

    // ---- epilogue: normalize, write bf16 for out-GEMM ----
    float linv[4];
#pragma unroll
    for (int e = 0; e < 4; ++e) {
        const int r32 = mi * 16 + quad * 4 + e;
        linv[e] = 1.0f / (psum[0][r32] + psum[1][r32] + psum[2][r32] + psum[3][r32]);
    }
#pragma unroll
    for (int t = 0; t < 2; ++t) {
        const int nj = (wv & 1) * 2 + t;
#pragma unroll
        for (int e = 0; e < 4; ++e) {
            const int r32 = mi * 16 + quad * 4 + e;
            const float val = oacc[t][e] * linv[e];
            const size_t idx = (size_t)(t0 + r32) * 512 + h * 64 + nj * 16 + col;
            abh[idx] = bfh(val);
        }
    }
}

// ---------------------------------------------------------------------------
extern "C" void kernel_launch(void* const* d_in, const int* in_sizes, int n_in,
                              void* d_out, int out_size, void* d_ws, size_t ws_size,
                              hipStream_t stream)
{
    const float* x  = (const float*)d_in[0];
    const float* Wq = (const float*)d_in[1];
    const float* bq = (const float*)d_in[2];
    const float* Wk = (const float*)d_in[3];
    const float* bk = (const float*)d_in[4];
    const float* Wv = (const float*)d_in[5];
    const float* bv = (const float*)d_in[6];
    const float* Wo = (const float*)d_in[7];
    const float* bo = (const float*)d_in[8];
    float* out = (float*)d_out;

    char* ws = (char*)d_ws;
    short* qb  = (short*)(ws);                          // 2 MB
    short* kb  = (short*)(ws + (2u << 20));             // 2 MB
    short* vbt = (short*)(ws + (4u << 20));             // 2 MB (transposed V)
    short* abh = (short*)(ws + (6u << 20));             // 2 MB (attn out bf16)
    short* xh  = (short*)(ws + (8u << 20));             // 2 MB
    short* xl  = (short*)(ws + (10u << 20));            // 2 MB
    short* wqb = (short*)(ws + (12u << 20));            // 0.5 MB each
    short* wkb = (short*)(ws + (12u << 20) + 1 * (512u << 10));
    short* wvb = (short*)(ws + (12u << 20) + 2 * (512u << 10));
    short* wob = (short*)(ws + (12u << 20) + 3 * (512u << 10));

    dim3 gp(128, 1, 5);
    prep<<<gp, 256, 0, stream>>>(x, Wq, Wk, Wv, Wo,
                                 xh, xl, wqb, wkb, wvb, wob);

    dim3 gq(DMODEL / 64, S_LEN / 32, 3);                // 8 x 64 x 3 = 1536 blocks
    gemm_qkv9<<<gq, 128, 0, stream>>>(xh, xl, wqb, wkb, wvb,
                                      bq, bk, bv, qb, kb, vbt);

    dim3 ga(NHEADS, S_LEN / 32);                        // 512 blocks
    banded_attn7<<<ga, 256, 0, stream>>>(qb, kb, vbt, abh);

    dim3 go(DMODEL / 64, S_LEN / 32);                   // 8 x 64 = 512 blocks
    gemm_out9<<<go, 128, 0, stream>>>(abh, wob, bo, out);
}

// Round 5
// 112.019 us; speedup vs baseline: 2.7999x; 1.0284x over previous
//
#include <hip/hip_runtime.h>
#include <hip/hip_bf16.h>
#include <math.h>

#define S_LEN  2048
#define DMODEL 512
#define NHEADS 8
#define DK     64
#define WIN    64

static constexpr float SCALE = 0.125f;

typedef short bf16x8 __attribute__((ext_vector_type(8)));
typedef float f32x4  __attribute__((ext_vector_type(4)));

// ---------------------------------------------------------------------------
// helpers
// ---------------------------------------------------------------------------
__device__ __forceinline__ short bfh(float v)
{
    __hip_bfloat16 b = __float2bfloat16(v);
    return *reinterpret_cast<short*>(&b);
}
__device__ __forceinline__ float bf2f(short s)
{
    __hip_bfloat16 b = *reinterpret_cast<__hip_bfloat16*>(&s);
    return __bfloat162float(b);
}
__device__ __forceinline__ void split1(float v, short& h, short& l)
{
    h = bfh(v);
    l = bfh(v - bf2f(h));
}

// async global->LDS, 16B per lane; lds dest = wave-uniform base + lane*16
__device__ __forceinline__ void dma16(const void* g, void* l)
{
    __builtin_amdgcn_global_load_lds(
        (const __attribute__((address_space(1))) unsigned int*)g,
        (__attribute__((address_space(3))) unsigned int*)l, 16, 0, 0);
}

// ---------------------------------------------------------------------------
// prep: z=0 -> x split into (xh, xl); z=1..4 -> W cast to bf16
// ---------------------------------------------------------------------------
__global__ __launch_bounds__(256)
void prep(const float* __restrict__ x,
          const float* __restrict__ wq, const float* __restrict__ wk,
          const float* __restrict__ wv, const float* __restrict__ wo,
          short* __restrict__ xh, short* __restrict__ xl,
          short* __restrict__ wqb, short* __restrict__ wkb,
          short* __restrict__ wvb, short* __restrict__ wob)
{
    const int z = blockIdx.z;
    if (z == 0) {
        for (int i = blockIdx.x * 256 + threadIdx.x; i < 262144; i += gridDim.x * 256) {
            const float4 v = ((const float4*)x)[i];
            short4 h4, l4;
            split1(v.x, h4.x, l4.x);
            split1(v.y, h4.y, l4.y);
            split1(v.z, h4.z, l4.z);
            split1(v.w, h4.w, l4.w);
            ((short4*)xh)[i] = h4;
            ((short4*)xl)[i] = l4;
        }
    } else {
        const float* s; short* d;
        switch (z) {
            case 1:  s = wq; d = wqb; break;
            case 2:  s = wk; d = wkb; break;
            case 3:  s = wv; d = wvb; break;
            default: s = wo; d = wob; break;
        }
        for (int i = blockIdx.x * 256 + threadIdx.x; i < 65536; i += gridDim.x * 256) {
            const float4 v = ((const float4*)s)[i];
            short4 o;
            o.x = bfh(v.x); o.y = bfh(v.y); o.z = bfh(v.z); o.w = bfh(v.w);
            ((short4*)d)[i] = o;
        }
    }
}

// ---------------------------------------------------------------------------
// QKV GEMM: 32-row x 64-col tiles, grid (8,64,3) = 1536 blocks (6/CU),
// 128 thr = 2 waves. W (bf16) staged via DMA in 4 phases x 16 KB with
// XOR chunk swizzle; A = pre-split xh/xl read straight from global.
// Inner loop is pure load + ds_read + MFMA (no conversion VALU).
// z=0 -> Q bf16, z=1 -> K bf16, z=2 -> V^T bf16 [dim][pos].
// (exact round-0 structure: 16 KB LDS -> high co-residency is the
//  latency-hiding mechanism; dbuf/full-K variants both regressed ~4us)
// ---------------------------------------------------------------------------
__global__ __launch_bounds__(128)
void gemm_qkv7(const short* __restrict__ xh, const short* __restrict__ xl,
               const short* __restrict__ wqb, const short* __restrict__ wkb,
               const short* __restrict__ wvb,
               const float* __restrict__ bq, const float* __restrict__ bk,
               const float* __restrict__ bv,
               short* __restrict__ qb, short* __restrict__ kb,
               short* __restrict__ vbt)
{
    __shared__ __align__(16) short sW[64 * 128];   // 16 KB: 64 cols x 128 k

    const int z = blockIdx.z;
    const short* Bg   = (z == 0) ? wqb : (z == 1) ? wkb : wvb;
    const float* bias = (z == 0) ? bq  : (z == 1) ? bk  : bv;
    const int row0 = blockIdx.y * 32;
    const int col0 = blockIdx.x * 64;
    const int tid  = threadIdx.x;
    const int lane = tid & 63;
    const int wv   = tid >> 6;
    const int col  = lane & 15;
    const int quad = lane >> 4;
    const int m    = row0 + wv * 16 + col;       // this wave's A row

    f32x4 acc[4];
#pragma unroll
    for (int nj = 0; nj < 4; ++nj)
        acc[nj] = (f32x4)0.0f;

    for (int ph = 0; ph < 4; ++ph) {
        __syncthreads();   // previous phase's LDS reads done
        // stage 64 rows x 16 chunks (16B) = 16 issues; issue i = rows 4i..4i+3
        for (int i = wv; i < 16; i += 2) {
            const int r = i * 4 + (lane >> 4);
            const int c = lane & 15;
            const int j = c ^ (r & 7);
            dma16(Bg + (size_t)(col0 + r) * 512 + ph * 128 + j * 8, sW + i * 512);
        }
        __syncthreads();   // DMA drain

#pragma unroll
        for (int kc = 0; kc < 4; ++kc) {
            const size_t aoff = (size_t)m * 512 + ph * 128 + kc * 32 + quad * 8;
            const bf16x8 ah = *(const bf16x8*)(xh + aoff);
            const bf16x8 al = *(const bf16x8*)(xl + aoff);
#pragma unroll
            for (int nj = 0; nj < 4; ++nj) {
                const int n = nj * 16 + col;
                const int c = kc * 4 + quad;
                const bf16x8 bf = *(const bf16x8*)&sW[n * 128 + (c ^ (n & 7)) * 8];
                acc[nj] = __builtin_amdgcn_mfma_f32_16x16x32_bf16(ah, bf, acc[nj], 0, 0, 0);
                acc[nj] = __builtin_amdgcn_mfma_f32_16x16x32_bf16(al, bf, acc[nj], 0, 0, 0);
            }
        }
    }

    // epilogue
#pragma unroll
    for (int nj = 0; nj < 4; ++nj) {
        const int cc = col0 + nj * 16 + col;
        const float bias_v = bias[cc];
#pragma unroll
        for (int e = 0; e < 4; ++e) {
            const int row = row0 + wv * 16 + quad * 4 + e;
            const float val = acc[nj][e] + bias_v;
            if (z == 0) {
                qb[(size_t)row * 512 + cc] = bfh(val);        // single bf16 Q
            } else if (z == 1) {
                kb[(size_t)row * 512 + cc] = bfh(val);
            } else {
                vbt[(size_t)cc * 2048 + row] = bfh(val);      // transposed
            }
        }
    }
}

// ---------------------------------------------------------------------------
// Output projection: same staging shape; A = attn output bf16 (direct).
// grid (8,64) = 512 blocks, 128 thr.  (exact round-0 structure)
// ---------------------------------------------------------------------------
__global__ __launch_bounds__(128)
void gemm_out7(const short* __restrict__ ah_g,
               const short* __restrict__ wob, const float* __restrict__ bo,
               float* __restrict__ out)
{
    __shared__ __align__(16) short sW[64 * 128];   // 16 KB

    const int row0 = blockIdx.y * 32;
    const int col0 = blockIdx.x * 64;
    const int tid  = threadIdx.x;
    const int lane = tid & 63;
    const int wv   = tid >> 6;
    const int col  = lane & 15;
    const int quad = lane >> 4;
    const int m    = row0 + wv * 16 + col;

    f32x4 acc[4];
#pragma unroll
    for (int nj = 0; nj < 4; ++nj)
        acc[nj] = (f32x4)0.0f;

    for (int ph = 0; ph < 4; ++ph) {
        __syncthreads();
        for (int i = wv; i < 16; i += 2) {
            const int r = i * 4 + (lane >> 4);
            const int c = lane & 15;
            const int j = c ^ (r & 7);
            dma16(wob + (size_t)(col0 + r) * 512 + ph * 128 + j * 8, sW + i * 512);
        }
        __syncthreads();

#pragma unroll
        for (int kc = 0; kc < 4; ++kc) {
            const bf16x8 af = *(const bf16x8*)(ah_g + (size_t)m * 512 + ph * 128 + kc * 32 + quad * 8);
#pragma unroll
            for (int nj = 0; nj < 4; ++nj) {
                const int n = nj * 16 + col;
                const int c = kc * 4 + quad;
                const bf16x8 bf = *(const bf16x8*)&sW[n * 128 + (c ^ (n & 7)) * 8];
                acc[nj] = __builtin_amdgcn_mfma_f32_16x16x32_bf16(af, bf, acc[nj], 0, 0, 0);
            }
        }
    }

#pragma unroll
    for (int nj = 0; nj < 4; ++nj) {
        const int cc = col0 + nj * 16 + col;
        const float bias_v = bo[cc];
#pragma unroll
        for (int e = 0; e < 4; ++e) {
            const int row = row0 + wv * 16 + quad * 4 + e;
            out[(size_t)row * 512 + cc] = acc[nj][e] + bias_v;
        }
    }
}

// ---------------------------------------------------------------------------
// MFMA banded attention v7: round-0 body, but V^T staging is issued AFTER
// the Q/K drain and flies under QK^T+max compute (T14 async-stage split).
// Same LDS / grid / occupancy as round-0 -> isolates the split-V change.
// Block = (head, 32-q tile), 256 thr = 4 waves.
// ---------------------------------------------------------------------------
__global__ __launch_bounds__(256)
void banded_attn7(const short* __restrict__ qb, const short* __restrict__ kb,
                  const short* __restrict__ vbt, short* __restrict__ abh)
{
    __shared__ __align__(16) short VtS[64 * 256];   // V^T [dim][32 chunks]
    __shared__ __align__(16) short KS [192 * 64];   // K window; aliased by P
    __shared__ __align__(16) short QS [32 * 64];
    __shared__ float pmax[4][32];
    __shared__ float psum[4][32];
    short* PS = KS;                                 // P [32][200], after QK

    const int h    = blockIdx.x;
    const int t0   = blockIdx.y * 32;
    const int tid  = threadIdx.x;
    const int lane = tid & 63;
    const int wv   = tid >> 6;
    const int col  = lane & 15;
    const int quad = lane >> 4;

    // ---- DMA staging: Q (4 issues), K (24) — 8-row groups of 128B ----
    {
        const int lr = lane >> 3;
        const int lc = lane & 7;
        for (int i = wv; i < 28; i += 4) {
            const short* src; short* dst; int r;
            if (i < 4) {
                r = i * 8 + lr;
                src = qb + (size_t)(t0 + r) * 512 + h * 64;
                dst = QS + i * 512;
            } else {
                const int g = i - 4;
                r = g * 8 + lr;
                int pos = t0 - 64 + r;
                pos = pos < 0 ? 0 : (pos > 2047 ? 2047 : pos);   // masked later
                src = kb + (size_t)pos * 512 + h * 64;
                dst = KS + g * 512;
            }
            const int cs = lc ^ (r & 7);
            dma16(src + cs * 8, dst);
        }
    }
    __syncthreads();   // drain Q+K only (28 KB) — V not yet issued

    // ---- V^T window issued now: flies under QK^T + max compute ----
    for (int i = wv; i < 32; i += 4) {
        const int q = i * 64 + lane;
        const int d = q >> 5;            // dim 0..63
        const int b = q & 31;            // dest chunk in row
        const int j0 = (b < 24) ? b : 0; // dead chunks load dummy
        const int j = j0 ^ (d & 7);
        int p0 = t0 - 64 + j * 8;
        p0 = p0 < 0 ? 0 : (p0 > 2040 ? 2040 : p0);
        dma16(vbt + (size_t)(h * 64 + d) * 2048 + p0, VtS + i * 512);
    }

    // ---- QK^T: wave covers positions [wv*48, wv*48+48) ----
    f32x4 sacc[2][3];
#pragma unroll
    for (int mi = 0; mi < 2; ++mi)
#pragma unroll
        for (int nj = 0; nj < 3; ++nj)
            sacc[mi][nj] = (f32x4)0.0f;

#pragma unroll
    for (int ks = 0; ks < 2; ++ks) {
        const int q0 = ks * 4 + quad;
        bf16x8 aq[2];
#pragma unroll
        for (int mi = 0; mi < 2; ++mi) {
            const int mm = mi * 16 + col;
            const int p = q0 ^ (mm & 7);
            aq[mi] = *(const bf16x8*)&QS[mm * 64 + p * 8];
        }
#pragma unroll
        for (int nj = 0; nj < 3; ++nj) {
            const int n = wv * 48 + nj * 16 + col;
            const int p = q0 ^ (n & 7);
            const bf16x8 bkf = *(const bf16x8*)&KS[n * 64 + p * 8];
#pragma unroll
            for (int mi = 0; mi < 2; ++mi)
                sacc[mi][nj] = __builtin_amdgcn_mfma_f32_16x16x32_bf16(aq[mi], bkf, sacc[mi][nj], 0, 0, 0);
        }
    }

    // ---- mask + scale ----
    float pv[2][3][4];
#pragma unroll
    for (int mi = 0; mi < 2; ++mi)
#pragma unroll
        for (int nj = 0; nj < 3; ++nj)
#pragma unroll
            for (int e = 0; e < 4; ++e) {
                const int r32 = mi * 16 + quad * 4 + e;
                const int n   = wv * 48 + nj * 16 + col;
                const int pos = t0 - 64 + n;
                const int d   = n - r32;
                const bool valid = (pos >= 0) && (pos < S_LEN) && (d >= 0) && (d <= 128);
                pv[mi][nj][e] = valid ? sacc[mi][nj][e] * SCALE : -__builtin_inff();
            }

    // ---- wave-partial row max ----
#pragma unroll
    for (int mi = 0; mi < 2; ++mi)
#pragma unroll
        for (int e = 0; e < 4; ++e) {
            float mx = fmaxf(fmaxf(pv[mi][0][e], pv[mi][1][e]), pv[mi][2][e]);
#pragma unroll
            for (int off = 1; off < 16; off <<= 1)
                mx = fmaxf(mx, __shfl_xor(mx, off));
            if ((lane & 15) == 0) pmax[wv][mi * 16 + quad * 4 + e] = mx;
        }
    __syncthreads();   // pmax done; K/Q reads done -> P may overwrite KS; V drained

    // ---- exp + wave-partial sums + write P (bf16) ----
#pragma unroll
    for (int mi = 0; mi < 2; ++mi)
#pragma unroll
        for (int e = 0; e < 4; ++e) {
            const int r32 = mi * 16 + quad * 4 + e;
            const float m = fmaxf(fmaxf(pmax[0][r32], pmax[1][r32]),
                                  fmaxf(pmax[2][r32], pmax[3][r32]));
            float ss = 0.f;
#pragma unroll
            for (int nj = 0; nj < 3; ++nj) {
                const float p = __expf(pv[mi][nj][e] - m);
                pv[mi][nj][e] = p;
                ss += p;
            }
#pragma unroll
            for (int off = 1; off < 16; off <<= 1)
                ss += __shfl_xor(ss, off);
            if ((lane & 15) == 0) psum[wv][r32] = ss;
#pragma unroll
            for (int nj = 0; nj < 3; ++nj) {
                const int n = wv * 48 + nj * 16 + col;
                PS[r32 * 200 + n] = bfh(pv[mi][nj][e]);
            }
        }
    __syncthreads();

    // ---- PV ----
    const int mi = wv >> 1;
    f32x4 oacc[2];
    oacc[0] = (f32x4)0.0f;
    oacc[1] = (f32x4)0.0f;
#pragma unroll
    for (int ks = 0; ks < 6; ++ks) {
        const bf16x8 pa = *(const bf16x8*)&PS[(mi * 16 + col) * 200 + ks * 32 + quad * 8];
#pragma unroll
        for (int t = 0; t < 2; ++t) {
            const int d = ((wv & 1) * 2 + t) * 16 + col;
            const int j = (ks * 4 + quad) ^ (d & 7);
            const bf16x8 vf = *(const bf16x8*)&VtS[d * 256 + j * 8];
            oacc[t] = __builtin_amdgcn_mfma_f32_16x16x32_bf16(pa, vf, oacc[t], 0, 0, 0);
        }
    }

    // ---- epilogue: normalize, write bf16 for out-GEMM ----
    float linv[4];
#pragma unroll
    for (int e = 0; e < 4; ++e) {
        const int r32 = mi * 16 + quad * 4 + e;
        linv[e] = 1.0f / (psum[0][r32] + psum[1][r32] + psum[2][r32] + psum[3][r32]);
    }
#pragma unroll
    for (int t = 0; t < 2; ++t) {
        const int nj = (wv & 1) * 2 + t;
#pragma unroll
        for (int e = 0; e < 4; ++e) {
            const int r32 = mi * 16 + quad * 4 + e;
            const float val = oacc[t][e] * linv[e];
            const size_t idx = (size_t)(t0 + r32) * 512 + h * 64 + nj * 16 + col;
            abh[idx] = bfh(val);
        }
    }
}

// ---------------------------------------------------------------------------
extern "C" void kernel_launch(void* const* d_in, const int* in_sizes, int n_in,
                              void* d_out, int out_size, void* d_ws, size_t ws_size,
                              hipStream_t stream)
{
    const float* x  = (const float*)d_in[0];
    const float* Wq = (const float*)d_in[1];
    const float* bq = (const float*)d_in[2];
    const float* Wk = (const float*)d_in[3];
    const float* bk = (const float*)d_in[4];
    const float* Wv = (const float*)d_in[5];
    const float* bv = (const float*)d_in[6];
    const float* Wo = (const float*)d_in[7];
    const float* bo = (const float*)d_in[8];
    float* out = (float*)d_out;

    char* ws = (char*)d_ws;
    short* qb  = (short*)(ws);                          // 2 MB
    short* kb  = (short*)(ws + (2u << 20));             // 2 MB
    short* vbt = (short*)(ws + (4u << 20));             // 2 MB (transposed V)
    short* abh = (short*)(ws + (6u << 20));             // 2 MB (attn out bf16)
    short* xh  = (short*)(ws + (8u << 20));             // 2 MB
    short* xl  = (short*)(ws + (10u << 20));            // 2 MB
    short* wqb = (short*)(ws + (12u << 20));            // 0.5 MB each
    short* wkb = (short*)(ws + (12u << 20) + 1 * (512u << 10));
    short* wvb = (short*)(ws + (12u << 20) + 2 * (512u << 10));
    short* wob = (short*)(ws + (12u << 20) + 3 * (512u << 10));

    dim3 gp(128, 1, 5);
    prep<<<gp, 256, 0, stream>>>(x, Wq, Wk, Wv, Wo,
                                 xh, xl, wqb, wkb, wvb, wob);

    dim3 gq(DMODEL / 64, S_LEN / 32, 3);                // 8 x 64 x 3 = 1536 blocks
    gemm_qkv7<<<gq, 128, 0, stream>>>(xh, xl, wqb, wkb, wvb,
                                      bq, bk, bv, qb, kb, vbt);

    dim3 ga(NHEADS, S_LEN / 32);                        // 512 blocks
    banded_attn7<<<ga, 256, 0, stream>>>(qb, kb, vbt, abh);

    dim3 go(DMODEL / 64, S_LEN / 32);                   // 8 x 64 = 512 blocks
    gemm_out7<<<go, 128, 0, stream>>>(abh, wob, bo, out);
}